// Round 1
// baseline (700.624 us; speedup 1.0000x reference)
//
#include <hip/hip_runtime.h>
#include <math.h>

#define ND 512
#define NK 32

// ---------------- mask dtype detection ----------------
// If mask arrives as 1-byte bools, 32-bit words frequently have value > 1
// (upper bytes set). If it arrives as int32 (0/1), no word exceeds 1.
__global__ void detect_mask_kernel(const unsigned int* __restrict__ m, int nwords,
                                   int* __restrict__ flag) {
  int local = 0;
  for (int i = blockIdx.x * blockDim.x + threadIdx.x; i < nwords;
       i += gridDim.x * blockDim.x) {
    if (m[i] > 1u) local = 1;
  }
  if (__any(local)) {
    if ((threadIdx.x & 63) == 0) atomicOr(flag, 1);
  }
}

// ---------------- GEMM: C[M,N] = op(A[M,K] @ B[N,K]^T) ----------------
// B row-major [N,K] (torch Linear weight layout).
// SPLIT: A is virtual concat(A1[M,512], A2[M,512]) along K (K=1024).
// TANH: apply tanhf epilogue.
// Tiles: BM=128, BN=64, BK=32; 256 threads; 8x4 per-thread microtile.
template<bool SPLIT, bool TANH>
__global__ __launch_bounds__(256, 2) void gemm_bt(
    const float* __restrict__ A1, const float* __restrict__ A2,
    const float* __restrict__ B, float* __restrict__ C,
    int M, int N, int K)
{
  __shared__ float As[32][132];  // [k][m], pad keeps 16B align + bank spread
  __shared__ float Bs[32][68];   // [k][n]
  const int tid = threadIdx.x;
  const int tx = tid & 15;       // n-dim
  const int ty = tid >> 4;       // m-dim
  const int bm = blockIdx.x * 128;
  const int bn = blockIdx.y * 64;
  const int lr = tid >> 3;          // 0..31 (tile row for loads)
  const int lc = (tid & 7) << 2;    // 0,4,...,28 (k-col for loads)

  float acc[8][4];
  #pragma unroll
  for (int i = 0; i < 8; i++)
    #pragma unroll
    for (int j = 0; j < 4; j++) acc[i][j] = 0.f;

  for (int kt = 0; kt < K; kt += 32) {
    // A tile: 128 rows x 32 k, transposed into LDS
    #pragma unroll
    for (int i = 0; i < 4; i++) {
      const int m = bm + lr + i * 32;
      float4 v = make_float4(0.f, 0.f, 0.f, 0.f);
      if (m < M) {
        const int kk = kt + lc;
        const float* src;
        if (SPLIT) src = (kk < ND) ? (A1 + (size_t)m * ND + kk)
                                   : (A2 + (size_t)m * ND + (kk - ND));
        else       src = A1 + (size_t)m * K + kk;
        v = *(const float4*)src;
      }
      As[lc + 0][lr + i * 32] = v.x;
      As[lc + 1][lr + i * 32] = v.y;
      As[lc + 2][lr + i * 32] = v.z;
      As[lc + 3][lr + i * 32] = v.w;
    }
    // B tile: 64 rows x 32 k (N=512 divides 64, no guard)
    #pragma unroll
    for (int i = 0; i < 2; i++) {
      const int nn = bn + lr + i * 32;
      const float4 v = *(const float4*)(B + (size_t)nn * K + kt + lc);
      Bs[lc + 0][lr + i * 32] = v.x;
      Bs[lc + 1][lr + i * 32] = v.y;
      Bs[lc + 2][lr + i * 32] = v.z;
      Bs[lc + 3][lr + i * 32] = v.w;
    }
    __syncthreads();
    #pragma unroll
    for (int kk = 0; kk < 32; kk++) {
      const float4 t0 = *(const float4*)&As[kk][ty * 8];
      const float4 t1 = *(const float4*)&As[kk][ty * 8 + 4];
      const float4 t2 = *(const float4*)&Bs[kk][tx * 4];
      float a[8], b[4];
      a[0] = t0.x; a[1] = t0.y; a[2] = t0.z; a[3] = t0.w;
      a[4] = t1.x; a[5] = t1.y; a[6] = t1.z; a[7] = t1.w;
      b[0] = t2.x; b[1] = t2.y; b[2] = t2.z; b[3] = t2.w;
      #pragma unroll
      for (int i = 0; i < 8; i++)
        #pragma unroll
        for (int j = 0; j < 4; j++)
          acc[i][j] = fmaf(a[i], b[j], acc[i][j]);
    }
    __syncthreads();
  }
  #pragma unroll
  for (int i = 0; i < 8; i++) {
    const int m = bm + ty * 8 + i;
    if (m < M) {
      float4 v;
      v.x = acc[i][0]; v.y = acc[i][1]; v.z = acc[i][2]; v.w = acc[i][3];
      if (TANH) {
        v.x = tanhf(v.x); v.y = tanhf(v.y); v.z = tanhf(v.z); v.w = tanhf(v.w);
      }
      *(float4*)(C + (size_t)m * N + bn + tx * 4) = v;
    }
  }
}

// ---------------- fused scores + softmax + aggregate ----------------
// One block (512 threads = 8 waves) per row n. Each wave owns 4 neighbors,
// holds their rows in registers between score and agg phases (neigh read ONCE).
__global__ __launch_bounds__(512) void attn_fused(
    const float* __restrict__ neigh,   // [N, 32, 512]
    const float* __restrict__ x,       // [N, 512]
    const void* __restrict__ mask,     // [N, 32] int32 or u8 (see flag)
    const int* __restrict__ mask_is_u8,
    float* __restrict__ agg)           // [N, 512]
{
  __shared__ float x_s[ND];
  __shared__ float part[8][ND];
  __shared__ float sc_s[NK];
  __shared__ float attn_s[NK];
  const int n = blockIdx.x;
  const int tid = threadIdx.x;
  const int wv = tid >> 6;
  const int lane = tid & 63;

  x_s[tid] = x[(size_t)n * ND + tid];
  __syncthreads();

  const float4 xa = *(const float4*)&x_s[lane * 4];
  const float4 xb = *(const float4*)&x_s[256 + lane * 4];

  // wave wv loads neighbors wv*4 .. wv*4+3 into registers (coalesced float4)
  const float4* nbase = (const float4*)(neigh + ((size_t)n * NK + wv * 4) * ND);
  float4 na[4], nb[4];
  #pragma unroll
  for (int j = 0; j < 4; j++) {
    na[j] = nbase[j * 128 + lane];
    nb[j] = nbase[j * 128 + 64 + lane];
  }

  // scores: 64-lane dot + butterfly reduce
  #pragma unroll
  for (int j = 0; j < 4; j++) {
    float p = na[j].x * xa.x + na[j].y * xa.y + na[j].z * xa.z + na[j].w * xa.w
            + nb[j].x * xb.x + nb[j].y * xb.y + nb[j].z * xb.z + nb[j].w * xb.w;
    #pragma unroll
    for (int off = 32; off; off >>= 1) p += __shfl_xor(p, off);
    if (lane == 0) sc_s[wv * 4 + j] = p;
  }
  __syncthreads();

  // masked softmax over 32 scores (threads 0..31, width-32 butterflies)
  if (tid < NK) {
    const int mk = (*mask_is_u8)
        ? (int)((const unsigned char*)mask)[(size_t)n * NK + tid]
        : ((const int*)mask)[(size_t)n * NK + tid];
    float s = mk ? -3.4e38f : sc_s[tid];
    float m = s;
    #pragma unroll
    for (int off = 16; off; off >>= 1) m = fmaxf(m, __shfl_xor(m, off, 32));
    const float p = mk ? 0.f : expf(s - m);
    float t = p;
    #pragma unroll
    for (int off = 16; off; off >>= 1) t += __shfl_xor(t, off, 32);
    attn_s[tid] = p / t;
  }
  __syncthreads();

  // agg: weighted sum of register-held neighbor rows, cross-wave sum via LDS
  float4 acc0 = make_float4(0.f, 0.f, 0.f, 0.f);
  float4 acc1 = make_float4(0.f, 0.f, 0.f, 0.f);
  #pragma unroll
  for (int j = 0; j < 4; j++) {
    const float w = attn_s[wv * 4 + j];
    acc0.x = fmaf(w, na[j].x, acc0.x);
    acc0.y = fmaf(w, na[j].y, acc0.y);
    acc0.z = fmaf(w, na[j].z, acc0.z);
    acc0.w = fmaf(w, na[j].w, acc0.w);
    acc1.x = fmaf(w, nb[j].x, acc1.x);
    acc1.y = fmaf(w, nb[j].y, acc1.y);
    acc1.z = fmaf(w, nb[j].z, acc1.z);
    acc1.w = fmaf(w, nb[j].w, acc1.w);
  }
  *(float4*)&part[wv][lane * 4] = acc0;
  *(float4*)&part[wv][256 + lane * 4] = acc1;
  __syncthreads();
  float ssum = 0.f;
  #pragma unroll
  for (int w = 0; w < 8; w++) ssum += part[w][tid];
  agg[(size_t)n * ND + tid] = ssum;
}

extern "C" void kernel_launch(void* const* d_in, const int* in_sizes, int n_in,
                              void* d_out, int out_size, void* d_ws, size_t ws_size,
                              hipStream_t stream) {
  const float* prev  = (const float*)d_in[0];   // [N, 512]
  const float* neigh = (const float*)d_in[1];   // [N, 32, 512]
  const void*  mask  = d_in[2];                 // [N, 32]
  const float* W1    = (const float*)d_in[3];   // [512, 512]
  const float* Wa    = (const float*)d_in[4];   // [512, 1024]
  float* out = (float*)d_out;
  const int N = in_sizes[0] / ND;               // 20000

  float* x    = (float*)d_ws;                   // [N,512]
  float* agg  = x + (size_t)N * ND;             // [N,512]
  int*   flag = (int*)(agg + (size_t)N * ND);

  // mask dtype detect (deterministic, data-derived)
  hipMemsetAsync(flag, 0, sizeof(int), stream);
  detect_mask_kernel<<<64, 256, 0, stream>>>((const unsigned int*)mask,
                                             (N * NK) / 4, flag);

  // x = prev @ W1^T
  dim3 g1((N + 127) / 128, ND / 64);
  gemm_bt<false, false><<<g1, 256, 0, stream>>>(prev, nullptr, W1, x, N, ND, ND);

  // scores -> softmax -> agg (neigh streamed once)
  attn_fused<<<N, 512, 0, stream>>>(neigh, x, mask, flag, agg);

  // out = tanh(concat(agg, prev) @ Wa^T)
  gemm_bt<true, true><<<g1, 256, 0, stream>>>(agg, prev, Wa, out, N, ND, 2 * ND);
}

// Round 2
// 478.541 us; speedup vs baseline: 1.4641x; 1.4641x over previous
//
#include <hip/hip_runtime.h>
#include <math.h>

#define ND 512
#define NK 32

typedef __attribute__((ext_vector_type(8))) short short8;
typedef __attribute__((ext_vector_type(4))) float f32x4;

__device__ inline unsigned short f2bf(float x) {
  unsigned u = __float_as_uint(x);
  unsigned r = (u + 0x7fffu + ((u >> 16) & 1u)) >> 16;  // RNE
  return (unsigned short)r;
}
__device__ inline float bf2f(unsigned short h) {
  return __uint_as_float(((unsigned)h) << 16);
}

// ---------------- mask dtype detection ----------------
__global__ void detect_mask_kernel(const unsigned int* __restrict__ m, int nwords,
                                   int* __restrict__ flag) {
  int local = 0;
  for (int i = blockIdx.x * blockDim.x + threadIdx.x; i < nwords;
       i += gridDim.x * blockDim.x) {
    if (m[i] > 1u) local = 1;
  }
  if (__any(local)) {
    if ((threadIdx.x & 63) == 0) atomicOr(flag, 1);
  }
}

// ---------------- split-bf16 MFMA GEMM: C[M,N] = op(A[M,K] @ B[N,K]^T) ----
// A,B f32 in HBM; staged to LDS as hi/lo bf16 pairs; 3 MFMA per frag pair
// (hh + hl + lh) gives ~f32 accuracy. 128x128 tile, BK=32, 256 thr / 4 waves,
// each wave a 64x64 quadrant (4x4 frags of 16x16x32).
// LDS row = 128B: 4 groups of [hi 16B | lo 16B]; XOR swizzle (row&7)<<4 on
// byte-in-row (involution; conflict-free ds_read_b128).
template<bool SPLIT, bool TANH>
__global__ __launch_bounds__(256, 2) void gemm_mfma(
    const float* __restrict__ A1, const float* __restrict__ A2,
    const float* __restrict__ B, float* __restrict__ C,
    int M, int N, int K)
{
  __shared__ unsigned char AsP[128 * 128];  // 16 KB
  __shared__ unsigned char BsP[128 * 128];  // 16 KB
  const int tid = threadIdx.x;
  const int lane = tid & 63;
  const int wv = tid >> 6;
  const int wr = wv >> 1, wc = wv & 1;
  const int bm = blockIdx.x * 128, bn = blockIdx.y * 128;

  // staging assignment: thread -> (row r0+32i, k-chunk kc..kc+3)
  const int r0 = tid >> 3;            // 0..31
  const int kc = (tid & 7) << 2;      // 0,4,...,28
  const int woff = 32 * (kc >> 3) + ((kc & 4) << 1);  // hi byte-in-row

  f32x4 acc[4][4];
  #pragma unroll
  for (int i = 0; i < 4; i++)
    #pragma unroll
    for (int j = 0; j < 4; j++) acc[i][j] = (f32x4){0.f, 0.f, 0.f, 0.f};

  const int s16 = (lane >> 4) * 32;   // k-slot byte base for frag reads

  for (int kt = 0; kt < K; kt += 32) {
    // ---- stage A tile (128 x 32 f32 -> hi/lo bf16) ----
    #pragma unroll
    for (int i = 0; i < 4; i++) {
      const int row = r0 + i * 32;
      const int m = bm + row;
      float4 v = make_float4(0.f, 0.f, 0.f, 0.f);
      const int kk = kt + kc;
      if (m < M) {
        const float* src;
        if (SPLIT) src = (kk < ND) ? (A1 + (size_t)m * ND + kk)
                                   : (A2 + (size_t)m * ND + (kk - ND));
        else       src = A1 + (size_t)m * K + kk;
        v = *(const float4*)src;
      }
      const unsigned short h0 = f2bf(v.x), h1 = f2bf(v.y),
                           h2 = f2bf(v.z), h3 = f2bf(v.w);
      const unsigned short l0 = f2bf(v.x - bf2f(h0)), l1 = f2bf(v.y - bf2f(h1)),
                           l2 = f2bf(v.z - bf2f(h2)), l3 = f2bf(v.w - bf2f(h3));
      uint2 hp, lp;
      hp.x = (unsigned)h0 | ((unsigned)h1 << 16);
      hp.y = (unsigned)h2 | ((unsigned)h3 << 16);
      lp.x = (unsigned)l0 | ((unsigned)l1 << 16);
      lp.y = (unsigned)l2 | ((unsigned)l3 << 16);
      const int sw = (row & 7) << 4;
      *(uint2*)(AsP + row * 128 + (woff ^ sw)) = hp;
      *(uint2*)(AsP + row * 128 + ((woff + 16) ^ sw)) = lp;
    }
    // ---- stage B tile (128 x 32 f32), rows are n-index; N % 128 == 0 ----
    #pragma unroll
    for (int i = 0; i < 4; i++) {
      const int row = r0 + i * 32;
      const float4 v = *(const float4*)(B + (size_t)(bn + row) * K + kt + kc);
      const unsigned short h0 = f2bf(v.x), h1 = f2bf(v.y),
                           h2 = f2bf(v.z), h3 = f2bf(v.w);
      const unsigned short l0 = f2bf(v.x - bf2f(h0)), l1 = f2bf(v.y - bf2f(h1)),
                           l2 = f2bf(v.z - bf2f(h2)), l3 = f2bf(v.w - bf2f(h3));
      uint2 hp, lp;
      hp.x = (unsigned)h0 | ((unsigned)h1 << 16);
      hp.y = (unsigned)h2 | ((unsigned)h3 << 16);
      lp.x = (unsigned)l0 | ((unsigned)l1 << 16);
      lp.y = (unsigned)l2 | ((unsigned)l3 << 16);
      const int sw = (row & 7) << 4;
      *(uint2*)(BsP + row * 128 + (woff ^ sw)) = hp;
      *(uint2*)(BsP + row * 128 + ((woff + 16) ^ sw)) = lp;
    }
    __syncthreads();

    // ---- MFMA: 4x4 frags x 3 (hh, hl, lh) ----
    short8 bh[4], bl[4];
    #pragma unroll
    for (int fn = 0; fn < 4; fn++) {
      const int row = wc * 64 + fn * 16 + (lane & 15);
      const int sw = (row & 7) << 4;
      bh[fn] = *(const short8*)(BsP + row * 128 + (s16 ^ sw));
      bl[fn] = *(const short8*)(BsP + row * 128 + ((s16 + 16) ^ sw));
    }
    #pragma unroll
    for (int fm = 0; fm < 4; fm++) {
      const int row = wr * 64 + fm * 16 + (lane & 15);
      const int sw = (row & 7) << 4;
      const short8 ah = *(const short8*)(AsP + row * 128 + (s16 ^ sw));
      const short8 al = *(const short8*)(AsP + row * 128 + ((s16 + 16) ^ sw));
      #pragma unroll
      for (int fn = 0; fn < 4; fn++) {
        acc[fm][fn] = __builtin_amdgcn_mfma_f32_16x16x32_bf16(ah, bh[fn], acc[fm][fn], 0, 0, 0);
        acc[fm][fn] = __builtin_amdgcn_mfma_f32_16x16x32_bf16(ah, bl[fn], acc[fm][fn], 0, 0, 0);
        acc[fm][fn] = __builtin_amdgcn_mfma_f32_16x16x32_bf16(al, bh[fn], acc[fm][fn], 0, 0, 0);
      }
    }
    __syncthreads();
  }

  // ---- epilogue: C/D map col=lane&15, row=(lane>>4)*4+j ----
  #pragma unroll
  for (int fm = 0; fm < 4; fm++) {
    #pragma unroll
    for (int fn = 0; fn < 4; fn++) {
      const int col = bn + wc * 64 + fn * 16 + (lane & 15);
      #pragma unroll
      for (int j = 0; j < 4; j++) {
        const int row = bm + wr * 64 + fm * 16 + (lane >> 4) * 4 + j;
        if (row < M) {
          float v = acc[fm][fn][j];
          if (TANH) v = tanhf(v);
          C[(size_t)row * N + col] = v;
        }
      }
    }
  }
}

// ---------------- fused scores + softmax + aggregate ----------------
__global__ __launch_bounds__(512) void attn_fused(
    const float* __restrict__ neigh,   // [N, 32, 512]
    const float* __restrict__ x,       // [N, 512]
    const void* __restrict__ mask,     // [N, 32] int32 or u8 (see flag)
    const int* __restrict__ mask_is_u8,
    float* __restrict__ agg)           // [N, 512]
{
  __shared__ float x_s[ND];
  __shared__ float part[8][ND];
  __shared__ float sc_s[NK];
  __shared__ float attn_s[NK];
  const int n = blockIdx.x;
  const int tid = threadIdx.x;
  const int wv = tid >> 6;
  const int lane = tid & 63;

  x_s[tid] = x[(size_t)n * ND + tid];
  __syncthreads();

  const float4 xa = *(const float4*)&x_s[lane * 4];
  const float4 xb = *(const float4*)&x_s[256 + lane * 4];

  const float4* nbase = (const float4*)(neigh + ((size_t)n * NK + wv * 4) * ND);
  float4 na[4], nb[4];
  #pragma unroll
  for (int j = 0; j < 4; j++) {
    na[j] = nbase[j * 128 + lane];
    nb[j] = nbase[j * 128 + 64 + lane];
  }

  #pragma unroll
  for (int j = 0; j < 4; j++) {
    float p = na[j].x * xa.x + na[j].y * xa.y + na[j].z * xa.z + na[j].w * xa.w
            + nb[j].x * xb.x + nb[j].y * xb.y + nb[j].z * xb.z + nb[j].w * xb.w;
    #pragma unroll
    for (int off = 32; off; off >>= 1) p += __shfl_xor(p, off);
    if (lane == 0) sc_s[wv * 4 + j] = p;
  }
  __syncthreads();

  if (tid < NK) {
    const int mk = (*mask_is_u8)
        ? (int)((const unsigned char*)mask)[(size_t)n * NK + tid]
        : ((const int*)mask)[(size_t)n * NK + tid];
    float s = mk ? -3.4e38f : sc_s[tid];
    float m = s;
    #pragma unroll
    for (int off = 16; off; off >>= 1) m = fmaxf(m, __shfl_xor(m, off, 32));
    const float p = mk ? 0.f : expf(s - m);
    float t = p;
    #pragma unroll
    for (int off = 16; off; off >>= 1) t += __shfl_xor(t, off, 32);
    attn_s[tid] = p / t;
  }
  __syncthreads();

  float4 acc0 = make_float4(0.f, 0.f, 0.f, 0.f);
  float4 acc1 = make_float4(0.f, 0.f, 0.f, 0.f);
  #pragma unroll
  for (int j = 0; j < 4; j++) {
    const float w = attn_s[wv * 4 + j];
    acc0.x = fmaf(w, na[j].x, acc0.x);
    acc0.y = fmaf(w, na[j].y, acc0.y);
    acc0.z = fmaf(w, na[j].z, acc0.z);
    acc0.w = fmaf(w, na[j].w, acc0.w);
    acc1.x = fmaf(w, nb[j].x, acc1.x);
    acc1.y = fmaf(w, nb[j].y, acc1.y);
    acc1.z = fmaf(w, nb[j].z, acc1.z);
    acc1.w = fmaf(w, nb[j].w, acc1.w);
  }
  *(float4*)&part[wv][lane * 4] = acc0;
  *(float4*)&part[wv][256 + lane * 4] = acc1;
  __syncthreads();
  float ssum = 0.f;
  #pragma unroll
  for (int w = 0; w < 8; w++) ssum += part[w][tid];
  agg[(size_t)n * ND + tid] = ssum;
}

extern "C" void kernel_launch(void* const* d_in, const int* in_sizes, int n_in,
                              void* d_out, int out_size, void* d_ws, size_t ws_size,
                              hipStream_t stream) {
  const float* prev  = (const float*)d_in[0];   // [N, 512]
  const float* neigh = (const float*)d_in[1];   // [N, 32, 512]
  const void*  mask  = d_in[2];                 // [N, 32]
  const float* W1    = (const float*)d_in[3];   // [512, 512]
  const float* Wa    = (const float*)d_in[4];   // [512, 1024]
  float* out = (float*)d_out;
  const int N = in_sizes[0] / ND;               // 20000

  float* x    = (float*)d_ws;                   // [N,512]
  float* agg  = x + (size_t)N * ND;             // [N,512]
  int*   flag = (int*)(agg + (size_t)N * ND);

  hipMemsetAsync(flag, 0, sizeof(int), stream);
  detect_mask_kernel<<<64, 256, 0, stream>>>((const unsigned int*)mask,
                                             (N * NK) / 4, flag);

  dim3 g1((N + 127) / 128, ND / 128);

  // x = prev @ W1^T
  gemm_mfma<false, false><<<g1, 256, 0, stream>>>(prev, nullptr, W1, x, N, ND, ND);

  // scores -> softmax -> agg (neigh streamed once)
  attn_fused<<<N, 512, 0, stream>>>(neigh, x, mask, flag, agg);

  // out = tanh(concat(agg, prev) @ Wa^T)
  gemm_mfma<true, true><<<g1, 256, 0, stream>>>(agg, prev, Wa, out, N, ND, 2 * ND);
}

// Round 3
// 423.504 us; speedup vs baseline: 1.6544x; 1.1300x over previous
//
#include <hip/hip_runtime.h>
#include <math.h>

#define ND 512
#define NK 32

typedef __attribute__((ext_vector_type(8))) short short8;
typedef __attribute__((ext_vector_type(4))) float f32x4;
typedef __attribute__((address_space(1))) const unsigned int glds_src;
typedef __attribute__((address_space(3))) unsigned int glds_dst;

__device__ inline unsigned short f2bf(float x) {
  unsigned u = __float_as_uint(x);
  unsigned r = (u + 0x7fffu + ((u >> 16) & 1u)) >> 16;  // RNE
  return (unsigned short)r;
}
__device__ inline float bf2f(unsigned short h) {
  return __uint_as_float(((unsigned)h) << 16);
}
__device__ inline void gload_lds16(const void* g, void* l) {
  __builtin_amdgcn_global_load_lds((glds_src*)g, (glds_dst*)l, 16, 0, 0);
}

// ---------------- mask dtype detection ----------------
__global__ void detect_mask_kernel(const unsigned int* __restrict__ m, int nwords,
                                   int* __restrict__ flag) {
  int local = 0;
  for (int i = blockIdx.x * blockDim.x + threadIdx.x; i < nwords;
       i += gridDim.x * blockDim.x) {
    if (m[i] > 1u) local = 1;
  }
  if (__any(local)) {
    if ((threadIdx.x & 63) == 0) atomicOr(flag, 1);
  }
}

// ---------------- panel converter ----------------
// Encode f32 [rows, Kd*32] row-major into per-row swizzled hi/lo bf16 image:
// row byte layout (per k-block kb, 128 B): 4 groups of [hi 16B | lo 16B] for
// k-slots s=0..3 (8 k each), XOR-swizzled by ((row&7)<<4) on byte-in-128B.
// Rows >= rows_src are zero-filled (padding).
__global__ void convert_panel(const float* __restrict__ src,
                              unsigned char* __restrict__ dst,
                              int rows_src, int rows_pad, int Kd) {
  const long long total = (long long)rows_pad * Kd * 4;
  const int cpr = Kd * 4;
  for (long long c = (long long)blockIdx.x * blockDim.x + threadIdx.x; c < total;
       c += (long long)gridDim.x * blockDim.x) {
    const int r = (int)(c / cpr);
    const int rem = (int)(c % cpr);
    const int kb = rem >> 2;
    const int s = rem & 3;
    const int sw = (r & 7) << 4;
    unsigned short h[8], l[8];
    if (r < rows_src) {
      const float* p = src + (size_t)r * (Kd * 32) + kb * 32 + s * 8;
      #pragma unroll
      for (int j = 0; j < 8; j++) {
        const float v = p[j];
        h[j] = f2bf(v);
        l[j] = f2bf(v - bf2f(h[j]));
      }
    } else {
      #pragma unroll
      for (int j = 0; j < 8; j++) { h[j] = 0; l[j] = 0; }
    }
    uint4 hv, lv;
    hv.x = (unsigned)h[0] | ((unsigned)h[1] << 16);
    hv.y = (unsigned)h[2] | ((unsigned)h[3] << 16);
    hv.z = (unsigned)h[4] | ((unsigned)h[5] << 16);
    hv.w = (unsigned)h[6] | ((unsigned)h[7] << 16);
    lv.x = (unsigned)l[0] | ((unsigned)l[1] << 16);
    lv.y = (unsigned)l[2] | ((unsigned)l[3] << 16);
    lv.z = (unsigned)l[4] | ((unsigned)l[5] << 16);
    lv.w = (unsigned)l[6] | ((unsigned)l[7] << 16);
    unsigned char* rowb = dst + (size_t)r * (Kd * 128) + kb * 128;
    *(uint4*)(rowb + ((s * 32) ^ sw)) = hv;
    *(uint4*)(rowb + ((s * 32 + 16) ^ sw)) = lv;
  }
}

// ---------------- split-bf16 MFMA GEMM on panel images ----------------
// C[M,N] = op(A @ B^T). A,B pre-encoded panel images (hi/lo bf16, swizzled).
// Staging = pure global_load_lds dwordx4 (image bytes == LDS bytes).
// 128x128 tile, BK=32 (1 k-block), 256 thr / 4 waves, 4x4 frags of 16x16x32,
// 3 MFMA per frag pair (hh + hl + lh).
template<bool SPLIT, bool TANH>
__global__ __launch_bounds__(256, 2) void gemm_mfma(
    const unsigned char* __restrict__ A1, const unsigned char* __restrict__ A2,
    const unsigned char* __restrict__ B, float* __restrict__ C,
    int M, int N, int KB)  // KB = k-blocks total (K = KB*32)
{
  __shared__ unsigned char AsP[16384];
  __shared__ unsigned char BsP[16384];
  const int tid = threadIdx.x;
  const int lane = tid & 63;
  const int wv = tid >> 6;
  const int wr = wv >> 1, wc = wv & 1;
  const int bm = blockIdx.y * 128, bn = blockIdx.x * 128;
  const size_t brstride = (size_t)KB * 128;
  const size_t arstride = SPLIT ? 2048 : (size_t)KB * 128;

  f32x4 acc[4][4];
  #pragma unroll
  for (int i = 0; i < 4; i++)
    #pragma unroll
    for (int j = 0; j < 4; j++) acc[i][j] = (f32x4){0.f, 0.f, 0.f, 0.f};

  const int s16 = (lane >> 4) * 32;
  const int lrow0 = (wv << 3) + (lane >> 3);   // 0..31
  const int lbyte = (lane & 7) * 16;

  for (int kb = 0; kb < KB; kb++) {
    const unsigned char* Ab;
    int akb;
    if (SPLIT) { Ab = (kb < 16) ? A1 : A2; akb = kb & 15; }
    else       { Ab = A1; akb = kb; }
    #pragma unroll
    for (int i = 0; i < 4; i++) {
      const int lrow = i * 32 + lrow0;
      gload_lds16(Ab + (size_t)(bm + lrow) * arstride + (size_t)akb * 128 + lbyte,
                  AsP + i * 4096 + wv * 1024);
      gload_lds16(B + (size_t)(bn + lrow) * brstride + (size_t)kb * 128 + lbyte,
                  BsP + i * 4096 + wv * 1024);
    }
    __syncthreads();

    short8 bh[4], bl[4];
    #pragma unroll
    for (int fn = 0; fn < 4; fn++) {
      const int row = wc * 64 + fn * 16 + (lane & 15);
      const int sw = (row & 7) << 4;
      bh[fn] = *(const short8*)(BsP + row * 128 + (s16 ^ sw));
      bl[fn] = *(const short8*)(BsP + row * 128 + ((s16 + 16) ^ sw));
    }
    #pragma unroll
    for (int fm = 0; fm < 4; fm++) {
      const int row = wr * 64 + fm * 16 + (lane & 15);
      const int sw = (row & 7) << 4;
      const short8 ah = *(const short8*)(AsP + row * 128 + (s16 ^ sw));
      const short8 al = *(const short8*)(AsP + row * 128 + ((s16 + 16) ^ sw));
      #pragma unroll
      for (int fn = 0; fn < 4; fn++) {
        acc[fm][fn] = __builtin_amdgcn_mfma_f32_16x16x32_bf16(ah, bh[fn], acc[fm][fn], 0, 0, 0);
        acc[fm][fn] = __builtin_amdgcn_mfma_f32_16x16x32_bf16(ah, bl[fn], acc[fm][fn], 0, 0, 0);
        acc[fm][fn] = __builtin_amdgcn_mfma_f32_16x16x32_bf16(al, bh[fn], acc[fm][fn], 0, 0, 0);
      }
    }
    __syncthreads();
  }

  // C/D map: col=lane&15, row=(lane>>4)*4+j
  #pragma unroll
  for (int fm = 0; fm < 4; fm++) {
    #pragma unroll
    for (int fn = 0; fn < 4; fn++) {
      const int col = bn + wc * 64 + fn * 16 + (lane & 15);
      #pragma unroll
      for (int j = 0; j < 4; j++) {
        const int row = bm + wr * 64 + fm * 16 + (lane >> 4) * 4 + j;
        if (row < M) {
          float v = acc[fm][fn][j];
          if (TANH) v = tanhf(v);
          C[(size_t)row * N + col] = v;
        }
      }
    }
  }
}

// ---------------- fused scores + softmax + aggregate ----------------
// One block (512 thr / 8 waves) per row; neigh streamed once through regs.
// Output written directly as panel image (hi/lo bf16, swizzled) for gemm2.
__global__ __launch_bounds__(512) void attn_fused(
    const float* __restrict__ neigh,   // [N, 32, 512]
    const float* __restrict__ x,       // [N, 512] f32
    const void* __restrict__ mask,     // [N, 32] int32 or u8 (see flag)
    const int* __restrict__ mask_is_u8,
    unsigned char* __restrict__ aggP)  // panel image, 2048 B/row
{
  __shared__ float x_s[ND];
  __shared__ float part[8][ND];
  __shared__ float sc_s[NK];
  __shared__ float attn_s[NK];
  __shared__ unsigned char img[2048];
  const int n = blockIdx.x;
  const int tid = threadIdx.x;
  const int wv = tid >> 6;
  const int lane = tid & 63;

  x_s[tid] = x[(size_t)n * ND + tid];
  __syncthreads();

  const float4 xa = *(const float4*)&x_s[lane * 4];
  const float4 xb = *(const float4*)&x_s[256 + lane * 4];

  const float4* nbase = (const float4*)(neigh + ((size_t)n * NK + wv * 4) * ND);
  float4 na[4], nb[4];
  #pragma unroll
  for (int j = 0; j < 4; j++) {
    na[j] = nbase[j * 128 + lane];
    nb[j] = nbase[j * 128 + 64 + lane];
  }

  #pragma unroll
  for (int j = 0; j < 4; j++) {
    float p = na[j].x * xa.x + na[j].y * xa.y + na[j].z * xa.z + na[j].w * xa.w
            + nb[j].x * xb.x + nb[j].y * xb.y + nb[j].z * xb.z + nb[j].w * xb.w;
    #pragma unroll
    for (int off = 32; off; off >>= 1) p += __shfl_xor(p, off);
    if (lane == 0) sc_s[wv * 4 + j] = p;
  }
  __syncthreads();

  if (tid < NK) {
    const int mk = (*mask_is_u8)
        ? (int)((const unsigned char*)mask)[(size_t)n * NK + tid]
        : ((const int*)mask)[(size_t)n * NK + tid];
    float s = mk ? -3.4e38f : sc_s[tid];
    float m = s;
    #pragma unroll
    for (int off = 16; off; off >>= 1) m = fmaxf(m, __shfl_xor(m, off, 32));
    const float p = mk ? 0.f : expf(s - m);
    float t = p;
    #pragma unroll
    for (int off = 16; off; off >>= 1) t += __shfl_xor(t, off, 32);
    attn_s[tid] = p / t;
  }
  __syncthreads();

  float4 acc0 = make_float4(0.f, 0.f, 0.f, 0.f);
  float4 acc1 = make_float4(0.f, 0.f, 0.f, 0.f);
  #pragma unroll
  for (int j = 0; j < 4; j++) {
    const float w = attn_s[wv * 4 + j];
    acc0.x = fmaf(w, na[j].x, acc0.x);
    acc0.y = fmaf(w, na[j].y, acc0.y);
    acc0.z = fmaf(w, na[j].z, acc0.z);
    acc0.w = fmaf(w, na[j].w, acc0.w);
    acc1.x = fmaf(w, nb[j].x, acc1.x);
    acc1.y = fmaf(w, nb[j].y, acc1.y);
    acc1.z = fmaf(w, nb[j].z, acc1.z);
    acc1.w = fmaf(w, nb[j].w, acc1.w);
  }
  *(float4*)&part[wv][lane * 4] = acc0;
  *(float4*)&part[wv][256 + lane * 4] = acc1;
  __syncthreads();
  float ssum = 0.f;
  #pragma unroll
  for (int w = 0; w < 8; w++) ssum += part[w][tid];

  // encode into panel-image row (k = tid)
  {
    const int sw = (n & 7) << 4;
    const int kb = tid >> 5;
    const int bu = ((tid >> 3) & 3) * 32 + (tid & 7) * 2;   // bit4 == 0
    const unsigned short h = f2bf(ssum);
    const unsigned short l = f2bf(ssum - bf2f(h));
    *(unsigned short*)(img + kb * 128 + (bu ^ sw)) = h;
    *(unsigned short*)(img + kb * 128 + ((bu | 16) ^ sw)) = l;
  }
  __syncthreads();
  if (tid < 128) {
    *(uint4*)(aggP + (size_t)n * 2048 + tid * 16) = *(const uint4*)(img + tid * 16);
  }
}

extern "C" void kernel_launch(void* const* d_in, const int* in_sizes, int n_in,
                              void* d_out, int out_size, void* d_ws, size_t ws_size,
                              hipStream_t stream) {
  const float* prev  = (const float*)d_in[0];   // [N, 512]
  const float* neigh = (const float*)d_in[1];   // [N, 32, 512]
  const void*  mask  = d_in[2];                 // [N, 32]
  const float* W1    = (const float*)d_in[3];   // [512, 512]
  const float* Wa    = (const float*)d_in[4];   // [512, 1024]
  float* out = (float*)d_out;
  const int N = in_sizes[0] / ND;               // 20000
  const int Mp = ((N + 127) / 128) * 128;       // 20096

  unsigned char* ws = (unsigned char*)d_ws;
  float*         x     = (float*)ws;                         // N*2048 B
  unsigned char* prevP = ws + (size_t)N * 2048;              // Mp*2048
  unsigned char* aggP  = prevP + (size_t)Mp * 2048;          // Mp*2048
  unsigned char* W1P   = aggP + (size_t)Mp * 2048;           // 512*2048
  unsigned char* WaP   = W1P + (size_t)512 * 2048;           // 512*4096
  int*           flag  = (int*)(WaP + (size_t)512 * 4096);

  hipMemsetAsync(flag, 0, sizeof(int), stream);
  detect_mask_kernel<<<64, 256, 0, stream>>>((const unsigned int*)mask,
                                             (N * NK) / 4, flag);

  // pre-encode GEMM operands into panel images
  convert_panel<<<2048, 256, 0, stream>>>(prev, prevP, N, Mp, 16);
  convert_panel<<<256, 256, 0, stream>>>(W1, W1P, 512, 512, 16);
  convert_panel<<<512, 256, 0, stream>>>(Wa, WaP, 512, 512, 32);
  // zero aggP padding rows (attn never writes them)
  if (Mp > N)
    hipMemsetAsync(aggP + (size_t)N * 2048, 0, (size_t)(Mp - N) * 2048, stream);

  dim3 g1(ND / 128, Mp / 128);  // bn fast -> blocks sharing A-panel adjacent

  // x = prev @ W1^T
  gemm_mfma<false, false><<<g1, 256, 0, stream>>>(prevP, nullptr, W1P, x, N, ND, 16);

  // scores -> softmax -> agg (neigh streamed once; agg emitted as panel image)
  attn_fused<<<N, 512, 0, stream>>>(neigh, x, mask, flag, aggP);

  // out = tanh(concat(agg, prev) @ Wa^T)
  gemm_mfma<true, true><<<g1, 256, 0, stream>>>(aggP, prevP, WaP, out, N, ND, 32);
}